// Round 1
// 381.182 us; speedup vs baseline: 1.0042x; 1.0042x over previous
//
#include <hip/hip_runtime.h>

#define V  32000
#define NB 16
#define L  128
#define LR 128

// ws layout (bytes):
//   [0, 1048576)           float probs[2048][128]   probs[(b*128+j)*128+i] = softmax(logits[b,j])[labels[b,i]]
//   [1048576, 1056768)     int   rowarg[2048]       argmax per (b,j) row
// (partial[] removed — rouge_final folded into rouge_match via atomicAdd on out)

// process one float4 (4 consecutive vocab entries starting at element 4*base)
#define PROC(vv, base, ss, mm, ii)                                              \
    {                                                                            \
        float x0 = (vv).x, x1 = (vv).y, x2 = (vv).z, x3 = (vv).w;               \
        ss += __expf(x0); if (x0 > mm) { mm = x0; ii = 4 * (base); }            \
        ss += __expf(x1); if (x1 > mm) { mm = x1; ii = 4 * (base) + 1; }        \
        ss += __expf(x2); if (x2 > mm) { mm = x2; ii = 4 * (base) + 2; }        \
        ss += __expf(x3); if (x3 > mm) { mm = x3; ii = 4 * (base) + 3; }        \
    }

__global__ __launch_bounds__(256) void rouge_softmax_rows(
    const float* __restrict__ logits, const int* __restrict__ labels,
    float* __restrict__ probs, int* __restrict__ rowarg, float* __restrict__ out)
{
    const int row = blockIdx.x;          // 0..2047 = b*128 + j
    const int b   = row >> 7;
    const int tid = threadIdx.x;
    const float* rowp = logits + (size_t)row * V;
    const float4* rowp4 = (const float4*)rowp;

    // init the scalar output once (stream order guarantees this lands before
    // rouge_match's atomics; out is re-poisoned by the harness every iter)
    if (row == 0 && tid == 0) out[0] = 1.0f;

    // PREFETCH the label-column gather now: the dependent use is after the full
    // 128 KB row scan, by which time the row is evicted from L2 (per-XCD working
    // set ~32 MB >> 4 MB).  Issuing the loads here hides their HBM latency under
    // the ~50 µs main loop instead of paying a serialized miss tail at the end.
    float labv = 0.0f;
    if (tid < LR) {
        int lab = labels[b * LR + tid];
        labv = rowp[lab];
    }

    // 8000 float4 per row = 7*1024 (main, 4-way unrolled) + 3*256 + 64 (tail)
    float s0 = 0.f, s1 = 0.f, s2 = 0.f, s3 = 0.f;
    float m0 = -3.0e38f, m1 = -3.0e38f, m2 = -3.0e38f, m3 = -3.0e38f;
    int   i0 = 0, i1 = 0, i2 = 0, i3 = 0;

    int c = tid;
#pragma unroll 1
    for (int k = 0; k < 7; ++k, c += 1024) {
        float4 v0 = rowp4[c];
        float4 v1 = rowp4[c + 256];
        float4 v2 = rowp4[c + 512];
        float4 v3 = rowp4[c + 768];
        PROC(v0, c,       s0, m0, i0);
        PROC(v1, c + 256, s1, m1, i1);
        PROC(v2, c + 512, s2, m2, i2);
        PROC(v3, c + 768, s3, m3, i3);
    }
    // tail: c == tid + 7168; indices tid+7168, +7424, +7680 all < 7936
    {
        float4 v0 = rowp4[c];
        float4 v1 = rowp4[c + 256];
        float4 v2 = rowp4[c + 512];
        PROC(v0, c,       s0, m0, i0);
        PROC(v1, c + 256, s1, m1, i1);
        PROC(v2, c + 512, s2, m2, i2);
        if (tid < 64) {
            float4 v3 = rowp4[7936 + tid];
            PROC(v3, 7936 + tid, s3, m3, i3);
        }
    }

    // merge 4 accumulator chains (tie-break: lower index wins)
    float s = (s0 + s1) + (s2 + s3);
    float m = m0; int mi = i0;
    if (m1 > m || (m1 == m && i1 < mi)) { m = m1; mi = i1; }
    if (m2 > m || (m2 == m && i2 < mi)) { m = m2; mi = i2; }
    if (m3 > m || (m3 == m && i3 < mi)) { m = m3; mi = i3; }

    // wave-64 butterfly reduction (no syncs)
    for (int off = 32; off > 0; off >>= 1) {
        float so = __shfl_xor(s,  off);
        float mo = __shfl_xor(m,  off);
        int   io = __shfl_xor(mi, off);
        s += so;
        if (mo > m || (mo == m && io < mi)) { m = mo; mi = io; }
    }

    __shared__ float ws_s[4]; __shared__ float ws_m[4]; __shared__ int ws_i[4];
    __shared__ float inv_s_sh;
    const int lane = tid & 63, wid = tid >> 6;
    if (lane == 0) { ws_s[wid] = s; ws_m[wid] = m; ws_i[wid] = mi; }
    __syncthreads();
    if (tid == 0) {
        float S = (ws_s[0] + ws_s[1]) + (ws_s[2] + ws_s[3]);
        float M = ws_m[0]; int I = ws_i[0];
#pragma unroll
        for (int k = 1; k < 4; ++k)
            if (ws_m[k] > M || (ws_m[k] == M && ws_i[k] < I)) { M = ws_m[k]; I = ws_i[k]; }
        rowarg[row] = I;
        inv_s_sh = 1.0f / S;
    }
    __syncthreads();

    // use the prefetched gather value — no HBM re-read here
    if (tid < LR) {
        probs[(size_t)row * LR + tid] = __expf(labv) * inv_s_sh;
    }
}

__global__ __launch_bounds__(256) void rouge_match(
    const int* __restrict__ labels, const float* __restrict__ probs,
    const int* __restrict__ rowarg, float* __restrict__ out)
{
    const int b = blockIdx.x;
    const int tid = threadIdx.x;
    __shared__ int lab_s[LR], hard_s[L], ji_s[LR], mj_s[L];
    __shared__ unsigned char r_s[LR];

    if (tid < LR) lab_s[tid] = labels[b * LR + tid];
    if (tid < L)  hard_s[tid] = rowarg[b * L + tid];
    __syncthreads();

    // row i -> first matching column j (cumsum(axis=-1)==1 dedup)
    if (tid < LR) {
        int ji = -1, lab = lab_s[tid];
        for (int j = 0; j < L; ++j) if (hard_s[j] == lab) { ji = j; break; }
        ji_s[tid] = ji;
    }
    __syncthreads();
    // column j -> first row i claiming it (cumsum(axis=-2)==1 dedup)
    if (tid < L) {
        int mj = -1;
        for (int i = 0; i < LR; ++i) if (ji_s[i] == tid) { mj = i; break; }
        mj_s[tid] = mj;
    }
    __syncthreads();
    // r_s[i]=1 iff row i survives the sudoku (its claimed column kept it)
    if (tid < LR) {
        int ji = ji_s[tid];
        r_s[tid] = (ji >= 0 && mj_s[ji] == tid) ? 1 : 0;
    }
    __syncthreads();

    float acc = 0.0f;
    const float* pb = probs + (size_t)b * L * LR;
    for (int p = tid; p < L * LR; p += 256) {
        int j = p >> 7;
        int i = p & (LR - 1);
        float pr = pb[p];
        int mj = mj_s[j];
        float w;
        if (mj == i)                      w = 1.0f;   // matched
        else if (mj < 0 && r_s[i] == 0)   w = 0.5f;   // row & col both unmatched
        else                              w = 0.1f;   // clip(0, 0.1)
        acc += w * pr;
    }

    // wave-64 shuffle reduce, then cross-wave via 4 LDS slots
    for (int off = 32; off > 0; off >>= 1) acc += __shfl_xor(acc, off);
    __shared__ float wsum[4];
    const int lane = tid & 63, wid = tid >> 6;
    if (lane == 0) wsum[wid] = acc;
    __syncthreads();
    if (tid == 0) {
        float t = (wsum[0] + wsum[1]) + (wsum[2] + wsum[3]);
        // denominators = Lr + L - n + 1 = 256; mean over B=16; numerators = -2*sum
        atomicAdd(out, -(2.0f / (256.0f * 16.0f)) * t);
    }
}

extern "C" void kernel_launch(void* const* d_in, const int* in_sizes, int n_in,
                              void* d_out, int out_size, void* d_ws, size_t ws_size,
                              hipStream_t stream) {
    const float* logits = (const float*)d_in[0];
    const int*   labels = (const int*)d_in[1];
    float* out = (float*)d_out;

    char* ws = (char*)d_ws;
    float* probs   = (float*)ws;                              // 2048*128 f32 = 1 MiB
    int*   rowarg  = (int*)(ws + (size_t)2048 * 128 * 4);     // 2048 i32

    rouge_softmax_rows<<<2048, 256, 0, stream>>>(logits, labels, probs, rowarg, out);
    rouge_match<<<NB, 256, 0, stream>>>(labels, probs, rowarg, out);
}

// Round 3
// 368.218 us; speedup vs baseline: 1.0395x; 1.0352x over previous
//
#include <hip/hip_runtime.h>

#define V  32000
#define NB 16
#define L  128
#define LR 128

// ws layout (bytes):
//   [0, 1048576)           float probs[2048][128]   probs[(b*128+j)*128+i] = softmax(logits[b,j])[labels[b,i]]
//   [1048576, 1056768)     int   rowarg[2048]       argmax per (b,j) row

// native clang vector type — __builtin_nontemporal_load rejects the HIP
// wrapper class float4, but accepts a true vector type.
typedef float fvec4 __attribute__((ext_vector_type(4)));

// non-temporal streaming load: logits are touched exactly once — evict-first in
// L2 so 262 MB of streaming traffic doesn't thrash the 32 MB aggregate L2.
#define LD_NT(p) __builtin_nontemporal_load(p)

// process one fvec4 (4 consecutive vocab entries starting at element 4*base)
#define PROC(vv, base, ss, mm, ii)                                              \
    {                                                                            \
        float x0 = (vv).x, x1 = (vv).y, x2 = (vv).z, x3 = (vv).w;               \
        ss += __expf(x0); if (x0 > mm) { mm = x0; ii = 4 * (base); }            \
        ss += __expf(x1); if (x1 > mm) { mm = x1; ii = 4 * (base) + 1; }        \
        ss += __expf(x2); if (x2 > mm) { mm = x2; ii = 4 * (base) + 2; }        \
        ss += __expf(x3); if (x3 > mm) { mm = x3; ii = 4 * (base) + 3; }        \
    }

__global__ __launch_bounds__(256) void rouge_softmax_rows(
    const float* __restrict__ logits, const int* __restrict__ labels,
    float* __restrict__ probs, int* __restrict__ rowarg, float* __restrict__ out)
{
    const int row = blockIdx.x;          // 0..2047 = b*128 + j
    const int b   = row >> 7;
    const int tid = threadIdx.x;
    const float* rowp = logits + (size_t)row * V;
    const fvec4* rowp4 = (const fvec4*)rowp;

    // init the scalar output once (stream order guarantees this lands before
    // rouge_match's atomics; out is re-poisoned by the harness every iter)
    if (row == 0 && tid == 0) out[0] = 1.0f;

    // PREFETCH the label-column gather (normal, cached loads): its HBM latency
    // hides under the ~50 µs scan, and the value is consumed at the very end.
    float labv = 0.0f;
    if (tid < LR) {
        int lab = labels[b * LR + tid];
        labv = rowp[lab];
    }

    // 8000 fvec4 per row = 7*1024 (main, 4-way unrolled) + 3*256 + 64 (tail)
    float s0 = 0.f, s1 = 0.f, s2 = 0.f, s3 = 0.f;
    float m0 = -3.0e38f, m1 = -3.0e38f, m2 = -3.0e38f, m3 = -3.0e38f;
    int   i0 = 0, i1 = 0, i2 = 0, i3 = 0;

    int c = tid;
#pragma unroll 1
    for (int k = 0; k < 7; ++k, c += 1024) {
        fvec4 v0 = LD_NT(&rowp4[c]);
        fvec4 v1 = LD_NT(&rowp4[c + 256]);
        fvec4 v2 = LD_NT(&rowp4[c + 512]);
        fvec4 v3 = LD_NT(&rowp4[c + 768]);
        PROC(v0, c,       s0, m0, i0);
        PROC(v1, c + 256, s1, m1, i1);
        PROC(v2, c + 512, s2, m2, i2);
        PROC(v3, c + 768, s3, m3, i3);
    }
    // tail: c == tid + 7168; indices tid+7168, +7424, +7680 all < 7936
    {
        fvec4 v0 = LD_NT(&rowp4[c]);
        fvec4 v1 = LD_NT(&rowp4[c + 256]);
        fvec4 v2 = LD_NT(&rowp4[c + 512]);
        PROC(v0, c,       s0, m0, i0);
        PROC(v1, c + 256, s1, m1, i1);
        PROC(v2, c + 512, s2, m2, i2);
        if (tid < 64) {
            fvec4 v3 = LD_NT(&rowp4[7936 + tid]);
            PROC(v3, 7936 + tid, s3, m3, i3);
        }
    }

    // merge 4 accumulator chains (tie-break: lower index wins)
    float s = (s0 + s1) + (s2 + s3);
    float m = m0; int mi = i0;
    if (m1 > m || (m1 == m && i1 < mi)) { m = m1; mi = i1; }
    if (m2 > m || (m2 == m && i2 < mi)) { m = m2; mi = i2; }
    if (m3 > m || (m3 == m && i3 < mi)) { m = m3; mi = i3; }

    // wave-64 butterfly reduction (no syncs)
    for (int off = 32; off > 0; off >>= 1) {
        float so = __shfl_xor(s,  off);
        float mo = __shfl_xor(m,  off);
        int   io = __shfl_xor(mi, off);
        s += so;
        if (mo > m || (mo == m && io < mi)) { m = mo; mi = io; }
    }

    __shared__ float ws_s[4]; __shared__ float ws_m[4]; __shared__ int ws_i[4];
    __shared__ float inv_s_sh;
    const int lane = tid & 63, wid = tid >> 6;
    if (lane == 0) { ws_s[wid] = s; ws_m[wid] = m; ws_i[wid] = mi; }
    __syncthreads();
    if (tid == 0) {
        float S = (ws_s[0] + ws_s[1]) + (ws_s[2] + ws_s[3]);
        float M = ws_m[0]; int I = ws_i[0];
#pragma unroll
        for (int k = 1; k < 4; ++k)
            if (ws_m[k] > M || (ws_m[k] == M && ws_i[k] < I)) { M = ws_m[k]; I = ws_i[k]; }
        rowarg[row] = I;
        inv_s_sh = 1.0f / S;
    }
    __syncthreads();

    // use the prefetched gather value — no HBM re-read here
    if (tid < LR) {
        probs[(size_t)row * LR + tid] = __expf(labv) * inv_s_sh;
    }
}

__global__ __launch_bounds__(256) void rouge_match(
    const int* __restrict__ labels, const float* __restrict__ probs,
    const int* __restrict__ rowarg, float* __restrict__ out)
{
    const int b = blockIdx.x;
    const int tid = threadIdx.x;
    __shared__ int lab_s[LR], hard_s[L], ji_s[LR], mj_s[L];
    __shared__ unsigned char r_s[LR];

    if (tid < LR) lab_s[tid] = labels[b * LR + tid];
    if (tid < L)  hard_s[tid] = rowarg[b * L + tid];
    __syncthreads();

    // row i -> first matching column j (cumsum(axis=-1)==1 dedup)
    if (tid < LR) {
        int ji = -1, lab = lab_s[tid];
        for (int j = 0; j < L; ++j) if (hard_s[j] == lab) { ji = j; break; }
        ji_s[tid] = ji;
    }
    __syncthreads();
    // column j -> first row i claiming it (cumsum(axis=-2)==1 dedup)
    if (tid < L) {
        int mj = -1;
        for (int i = 0; i < LR; ++i) if (ji_s[i] == tid) { mj = i; break; }
        mj_s[tid] = mj;
    }
    __syncthreads();
    // r_s[i]=1 iff row i survives the sudoku (its claimed column kept it)
    if (tid < LR) {
        int ji = ji_s[tid];
        r_s[tid] = (ji >= 0 && mj_s[ji] == tid) ? 1 : 0;
    }
    __syncthreads();

    float acc = 0.0f;
    const float* pb = probs + (size_t)b * L * LR;
    for (int p = tid; p < L * LR; p += 256) {
        int j = p >> 7;
        int i = p & (LR - 1);
        float pr = pb[p];
        int mj = mj_s[j];
        float w;
        if (mj == i)                      w = 1.0f;   // matched
        else if (mj < 0 && r_s[i] == 0)   w = 0.5f;   // row & col both unmatched
        else                              w = 0.1f;   // clip(0, 0.1)
        acc += w * pr;
    }

    // wave-64 shuffle reduce, then cross-wave via 4 LDS slots
    for (int off = 32; off > 0; off >>= 1) acc += __shfl_xor(acc, off);
    __shared__ float wsum[4];
    const int lane = tid & 63, wid = tid >> 6;
    if (lane == 0) wsum[wid] = acc;
    __syncthreads();
    if (tid == 0) {
        float t = (wsum[0] + wsum[1]) + (wsum[2] + wsum[3]);
        // denominators = Lr + L - n + 1 = 256; mean over B=16; numerators = -2*sum
        atomicAdd(out, -(2.0f / (256.0f * 16.0f)) * t);
    }
}

extern "C" void kernel_launch(void* const* d_in, const int* in_sizes, int n_in,
                              void* d_out, int out_size, void* d_ws, size_t ws_size,
                              hipStream_t stream) {
    const float* logits = (const float*)d_in[0];
    const int*   labels = (const int*)d_in[1];
    float* out = (float*)d_out;

    char* ws = (char*)d_ws;
    float* probs   = (float*)ws;                              // 2048*128 f32 = 1 MiB
    int*   rowarg  = (int*)(ws + (size_t)2048 * 128 * 4);     // 2048 i32

    rouge_softmax_rows<<<2048, 256, 0, stream>>>(logits, labels, probs, rowarg, out);
    rouge_match<<<NB, 256, 0, stream>>>(labels, probs, rowarg, out);
}